// Round 22
// baseline (62.968 us; speedup 1.0000x reference)
//
#include <hip/hip_runtime.h>

namespace {

constexpr int B = 4, S = 4096, H = 16, D = 32;
constexpr int L = 32;             // chunk length
constexpr int NC = S / L;         // 128 chunks per sequence
constexpr int NBH = B * H;        // 64
constexpr int RS = H * D;         // 512 floats between consecutive time steps
constexpr float GEPS = 1.52587890625e-05f;  // 2^-16 per-step decay clamp

// Lore (rounds 6-21, measured):
//  - launch_bounds(256,w) caps VGPR ~256/w; cap < live set => GB-scale spill.
//  - Scalar j-loops over LDS tiles are LDS-instruction bound -> MFMA.
//  - COLD scalar column loads are latency death (r13); OK L3-warm (r12).
//  - KVc MFMA needs TOTAL-scaled W; P MFMA needs SUB-scaled W (r15/r16).
//  - Pure consumers beat recomputing consumers (r16-19 all pinned ~48us).
//  - r21: f16 l export -> absmax 1.5 (ulp 0.25-0.5 at |l|~512). NEVER
//    quantize l; export BOUNDED scales (PS=2^{l-e_sub} bf16) + ES f32.
//  - r21: transpose-export mapping (mcol=tid>>3) -> 8-way LDS conflicts.
//    Use (mcol=tid&31, rq=(tid>>5)*4): 2-way (free), stores 64B-strided.
//  - MFMA operand convention (HW-verified r12, absmax 0.5):
//    A-op: row = lane&31, k = 8*(lane>>5)+e (+16 for 2nd MFMA)
//    B-op: col = lane&31, same k
//    C/D : col = lane&31, row = (reg&3)+8*(reg>>2)+4*(lane>>5)

typedef __attribute__((ext_vector_type(8)))  short short8v;   // 8 bf16 = 4 VGPR
typedef __attribute__((ext_vector_type(16))) float f32x16;    // 16 f32 acc

__device__ __forceinline__ float flog2(float x) { return __builtin_amdgcn_logf(x); }
__device__ __forceinline__ float fexp2(float x) { return __builtin_amdgcn_exp2f(x); }
__device__ __forceinline__ unsigned f2bfu(float f) {          // fp32 -> bf16 (RNE)
    unsigned u = __float_as_uint(f);
    return (u + 0x7FFFu + ((u >> 16) & 1u)) >> 16;
}
__device__ __forceinline__ short f2bf(float f) { return (short)f2bfu(f); }
__device__ __forceinline__ float bf2f(short s) {              // bf16 -> fp32
    return __uint_as_float(((unsigned)(ushort)s) << 16);
}
__device__ __forceinline__ float bfu2f(unsigned u16) {
    return __uint_as_float(u16 << 16);
}

// ---------------- Kernel 1: scan + W/PS export + chunk-KV MFMA ----------------
// One block per chunk (8192).
// lg: log2 g -> final l -> PS (overwritten in place).
// w_s = v*2^{e_sub(i)-l_i} (SUB-scaled, bf16).  PS_i = 2^{e_sub(i)-l_i}... NO:
//   PS_i = factor in W; exported PS = same fexp2(e4-l4). k3 uses PS as
//   2^{l_i-e_sub(i)}?? NOTE: e_sub >= ... l decreasing => l_i >= e_sub(i);
//   factor stored = 2^{e_sub - l_i} in (0,1]. k3 needs 2^{l_i - e_sub} = 1/PS?
//   -> store PSrec = fexp2(l4 - e4) (>=1, bounded 2^112) separately. One extra
//   fexp2 per element (cheap, trans pipe).
// Exports: WT[chunk][m][r] bf16, PST[chunk][m][r] bf16 (=2^{l-e_sub}),
//          ES[chunk][s][m] f32 (l at rows 8s+7).
// ChKV[chunk][d][m] bf16 (TOTAL-scaled MFMA).  ChG[chunk][m] = 2^{total}.
__global__ __launch_bounds__(256)
void k1_stage(const float* __restrict__ Kp, const float* __restrict__ Vp,
              const float* __restrict__ Gp, ushort* __restrict__ ChKV,
              float* __restrict__ ChG, ushort* __restrict__ WT,
              ushort* __restrict__ PST, float* __restrict__ ESb)
{
    __shared__ __align__(16) float  k_s[L][36];
    __shared__ __align__(16) float  lg[L][36];   // log2g -> l -> PS
    __shared__ __align__(16) ushort w_s[L][40];
    __shared__ float sub[8][D];
    __shared__ float es_s[4][D];

    const int blk = blockIdx.x;                   // == chunk == bh*NC + c
    const int bh = blk >> 7;
    const int c = blk & (NC - 1);
    const int b = bh >> 4;
    const int h = bh & (H - 1);
    const long base = ((long)b * S + (long)c * L) * RS + h * D;

    const int tid = threadIdx.x;
    const int i = tid >> 3;          // row 0..31
    const int u = (tid & 7) * 4;     // col quad
    const long roff = base + (long)i * RS + u;

    float4 k4 = *(const float4*)(Kp + roff);
    float4 v4 = *(const float4*)(Vp + roff);
    float4 g4 = *(const float4*)(Gp + roff);
    *(float4*)&k_s[i][u] = k4;
    float4 lv;
    lv.x = flog2(fmaxf(g4.x, GEPS));
    lv.y = flog2(fmaxf(g4.y, GEPS));
    lv.z = flog2(fmaxf(g4.z, GEPS));
    lv.w = flog2(fmaxf(g4.w, GEPS));
    *(float4*)&lg[i][u] = lv;
    __syncthreads();                               // b1

    // column scan: thread -> (column m, 4-row group t)
    const int m = tid & 31, t = tid >> 5;
    const int r0 = t * 4;
    float c0 = lg[r0 + 0][m];
    float c1 = c0 + lg[r0 + 1][m];
    float c2 = c1 + lg[r0 + 2][m];
    float c3 = c2 + lg[r0 + 3][m];
    sub[t][m] = c3;
    __syncthreads();                               // b2

    {
        float sb[8];
        float total = 0.f;
        #pragma unroll
        for (int tt = 0; tt < 8; ++tt) { sb[tt] = sub[tt][m]; total += sb[tt]; }
        float base_l = 0.f;
        #pragma unroll
        for (int tt = 0; tt < 8; ++tt) { if (tt < t) base_l += sb[tt]; }
        lg[r0 + 0][m] = base_l + c0;
        lg[r0 + 1][m] = base_l + c1;
        lg[r0 + 2][m] = base_l + c2;
        lg[r0 + 3][m] = base_l + c3;
        if (t & 1) es_s[t >> 1][m] = base_l + c3;  // l at rows 7,15,23,31
        if (t == 0) ChG[(long)blk * D + m] = fexp2(total);
    }
    __syncthreads();                               // b3 (lg final, es_s ready)

    // capture own l and sub-end BEFORE overwriting lg with PS
    float4 l4 = *(float4*)&lg[i][u];
    float4 e4 = *(float4*)&lg[i | 7][u];
    __syncthreads();                               // b4 (reads complete)

    // W = v*2^{e-l} (bf16), PS = 2^{l-e} (f32, in lg slot)
    {
        float4 ps;
        ps.x = fexp2(l4.x - e4.x); ps.y = fexp2(l4.y - e4.y);
        ps.z = fexp2(l4.z - e4.z); ps.w = fexp2(l4.w - e4.w);
        unsigned p0 = f2bfu(v4.x * fexp2(e4.x - l4.x))
                    | (f2bfu(v4.y * fexp2(e4.y - l4.y)) << 16);
        unsigned p1 = f2bfu(v4.z * fexp2(e4.z - l4.z))
                    | (f2bfu(v4.w * fexp2(e4.w - l4.w)) << 16);
        uint2 pp; pp.x = p0; pp.y = p1;
        *(uint2*)&w_s[i][u] = pp;
        *(float4*)&lg[i][u] = ps;
    }
    __syncthreads();                               // b5 (w_s, PS ready)

    // ---- transposed exports: (mcol = tid&31, rq = (tid>>5)*4) -> 2-way LDS ----
    {
        const int mcol = tid & 31;
        const int rq = (tid >> 5) * 4;
        uint2 wp, pp;
        ushort wq[4], pq[4];
        #pragma unroll
        for (int z = 0; z < 4; ++z) {
            wq[z] = w_s[rq + z][mcol];
            pq[z] = (ushort)f2bf(lg[rq + z][mcol]);
        }
        wp.x = (unsigned)wq[0] | ((unsigned)wq[1] << 16);
        wp.y = (unsigned)wq[2] | ((unsigned)wq[3] << 16);
        pp.x = (unsigned)pq[0] | ((unsigned)pq[1] << 16);
        pp.y = (unsigned)pq[2] | ((unsigned)pq[3] << 16);
        *(uint2*)(WT  + (long)blk * 1024 + mcol * 32 + rq) = wp;
        *(uint2*)(PST + (long)blk * 1024 + mcol * 32 + rq) = pp;
    }
    if (tid < 128) ESb[(long)blk * 128 + tid] = es_s[tid >> 5][tid & 31];

    // ---- wave 0: TOTAL-rescaled fragments + 2 MFMAs + bf16 ChKV store ----
    if (tid < 64) {
        const int half = tid >> 5;
        const int mm = tid & 31;
        const float es0_ = es_s[0][mm], es1_ = es_s[1][mm];
        const float es2_ = es_s[2][mm], es3_ = es_s[3][mm];   // es3_ == total
        const float fac0 = fexp2(es3_ - (half ? es1_ : es0_));
        const float fac1 = fexp2(es3_ - (half ? es3_ : es2_));
        short8v ka0, ka1, wf0, wf1;
        #pragma unroll
        for (int e = 0; e < 8; ++e) {
            ka0[e] = f2bf(k_s[8 * half + e][mm]);
            ka1[e] = f2bf(k_s[16 + 8 * half + e][mm]);
            wf0[e] = f2bf(bf2f((short)w_s[8 * half + e][mm]) * fac0);
            wf1[e] = f2bf(bf2f((short)w_s[16 + 8 * half + e][mm]) * fac1);
        }
        f32x16 acc;
        #pragma unroll
        for (int e = 0; e < 16; ++e) acc[e] = 0.f;
        acc = __builtin_amdgcn_mfma_f32_32x32x16_bf16(ka0, wf0, acc, 0, 0, 0);
        acc = __builtin_amdgcn_mfma_f32_32x32x16_bf16(ka1, wf1, acc, 0, 0, 0);

        ushort* kvout = ChKV + (long)blk * (D * D);
        #pragma unroll
        for (int reg = 0; reg < 16; ++reg) {
            const int d = (reg & 3) + 8 * (reg >> 2) + 4 * half;
            kvout[d * D + mm] = (ushort)f2bf(acc[reg]);
        }
    }
}

// ---------------- Kernel 2: inter-chunk scan (bf16 in/out, f32 state) --------
__global__ __launch_bounds__(256)
void k2_scan(ushort* __restrict__ ChKV, const float* __restrict__ ChG)
{
    const int bh = blockIdx.x >> 2;
    const int dg = blockIdx.x & 3;
    const int tid = threadIdx.x;
    const int d = dg * 8 + (tid >> 5);
    const int m = tid & 31;

    const long kvoff = (long)bh * NC * (D * D) + d * D + m;
    const long goff = (long)bh * NC * D + m;

    ushort ka[8]; float ga[8];
    #pragma unroll
    for (int t = 0; t < 8; ++t) {
        ka[t] = ChKV[kvoff + (long)t * (D * D)];
        ga[t] = ChG[goff + (long)t * D];
    }
    float st = 0.f;
    for (int c0 = 0; c0 < NC; c0 += 8) {
        ushort kb[8]; float gb2[8];
        const bool more = (c0 + 8) < NC;
        #pragma unroll
        for (int t = 0; t < 8; ++t) {
            kb[t]  = more ? ChKV[kvoff + (long)(c0 + 8 + t) * (D * D)] : (ushort)0;
            gb2[t] = more ? ChG[goff + (long)(c0 + 8 + t) * D] : 0.f;
        }
        #pragma unroll
        for (int t = 0; t < 8; ++t) {
            ChKV[kvoff + (long)(c0 + t) * (D * D)] = (ushort)f2bf(st); // START
            st = ga[t] * st + bf2f((short)ka[t]);
        }
        #pragma unroll
        for (int t = 0; t < 8; ++t) { ka[t] = kb[t]; ga[t] = gb2[t]; }
    }
}

// ---------------- Kernel 3: pure-consumer MFMA outputs ------------------------
// One wave per chunk; 4 chunks per block; ONE barrier.
// Reads Q,K (b128), WT (2 b128), PST (4 b64), ES (4 coalesced f32), S0 (16 bf16).
__global__ __launch_bounds__(256)
void k3_mfma(const float* __restrict__ Qp, const float* __restrict__ Kp,
             const ushort* __restrict__ WT, const ushort* __restrict__ PST,
             const float* __restrict__ ESb, const ushort* __restrict__ S0b,
             float* __restrict__ Op)
{
    __shared__ __align__(16) ushort a_s[4][L][40];   // masked Gram, bf16

    const int tid = threadIdx.x;
    const int wv = tid >> 6;
    const int lane = tid & 63;
    const int half = lane >> 5;
    const int m = lane & 31;

    const int chunk = blockIdx.x * 4 + wv;
    const int bh = chunk >> 7;
    const int c = chunk & (NC - 1);
    const int b = bh >> 4;
    const int h = bh & (H - 1);
    const long base = ((long)b * S + (long)c * L) * RS + h * D;
    const ushort* S0c = S0b + (long)chunk * (D * D);

    // Q/K fragments (row-major b128)
    const float* qrow = Qp + base + (long)m * RS + 8 * half;
    const float* krow = Kp + base + (long)m * RS + 8 * half;
    float4 qv0 = *(const float4*)(qrow);
    float4 qv1 = *(const float4*)(qrow + 4);
    float4 qv2 = *(const float4*)(qrow + 16);
    float4 qv3 = *(const float4*)(qrow + 20);
    float4 kv0 = *(const float4*)(krow);
    float4 kv1 = *(const float4*)(krow + 4);
    float4 kv2 = *(const float4*)(krow + 16);
    float4 kv3 = *(const float4*)(krow + 20);
    short8v qa0, qa1, ka0, ka1;
    {
        float qf[16] = {qv0.x,qv0.y,qv0.z,qv0.w, qv1.x,qv1.y,qv1.z,qv1.w,
                        qv2.x,qv2.y,qv2.z,qv2.w, qv3.x,qv3.y,qv3.z,qv3.w};
        float kf[16] = {kv0.x,kv0.y,kv0.z,kv0.w, kv1.x,kv1.y,kv1.z,kv1.w,
                        kv2.x,kv2.y,kv2.z,kv2.w, kv3.x,kv3.y,kv3.z,kv3.w};
        #pragma unroll
        for (int e = 0; e < 8; ++e) {
            qa0[e] = f2bf(qf[e]);     qa1[e] = f2bf(qf[8 + e]);
            ka0[e] = f2bf(kf[e]);     ka1[e] = f2bf(kf[8 + e]);
        }
    }

    // W fragments: 2 b128 from WT[chunk][m][.]
    const ushort* Wc = WT + (long)chunk * 1024 + m * 32;
    const short8v wf0 = *(const short8v*)(Wc + 8 * half);
    const short8v wf1 = *(const short8v*)(Wc + 16 + 8 * half);

    // PS at this lane's C-rows: 4 b64 from PST (rows 8j+4h .. +3)
    const ushort* Pc = PST + (long)chunk * 1024 + m * 32;
    float ps[16];
    #pragma unroll
    for (int j = 0; j < 4; ++j) {
        uint2 pp = *(const uint2*)(Pc + 8 * j + 4 * half);
        ps[4 * j + 0] = bfu2f(pp.x & 0xFFFFu);
        ps[4 * j + 1] = bfu2f(pp.x >> 16);
        ps[4 * j + 2] = bfu2f(pp.y & 0xFFFFu);
        ps[4 * j + 3] = bfu2f(pp.y >> 16);
    }
    // ES: l at rows 8s+7 (coalesced f32)
    float es4[4];
    #pragma unroll
    for (int s = 0; s < 4; ++s) es4[s] = ESb[(long)chunk * 128 + s * 32 + m];

    // Gram A = Q.K^T -> masked bf16 a_s
    {
        f32x16 acc;
        #pragma unroll
        for (int e = 0; e < 16; ++e) acc[e] = 0.f;
        acc = __builtin_amdgcn_mfma_f32_32x32x16_bf16(qa0, ka0, acc, 0, 0, 0);
        acc = __builtin_amdgcn_mfma_f32_32x32x16_bf16(qa1, ka1, acc, 0, 0, 0);
        #pragma unroll
        for (int reg = 0; reg < 16; ++reg) {
            const int irow = (reg & 3) + 8 * (reg >> 2) + 4 * half;
            const float av = (m <= irow) ? acc[reg] : 0.f;
            a_s[wv][irow][m] = (ushort)f2bf(av);
        }
    }

    // cross-chunk: PS * 2^{ES[sub]} * (Q.S0)   (sub(irow) == reg>>2)
    f32x16 sacc;
    #pragma unroll
    for (int e = 0; e < 16; ++e) sacc[e] = 0.f;
    {
        short8v sf0, sf1;
        #pragma unroll
        for (int e = 0; e < 8; ++e) {
            sf0[e] = (short)S0c[(8 * half + e) * D + m];
            sf1[e] = (short)S0c[(16 + 8 * half + e) * D + m];
        }
        sacc = __builtin_amdgcn_mfma_f32_32x32x16_bf16(qa0, sf0, sacc, 0, 0, 0);
        sacc = __builtin_amdgcn_mfma_f32_32x32x16_bf16(qa1, sf1, sacc, 0, 0, 0);
    }
    float subsc[4];
    #pragma unroll
    for (int s = 0; s < 4; ++s) subsc[s] = fexp2(es4[s]);  // underflow->0 OK
    f32x16 out;
    #pragma unroll
    for (int reg = 0; reg < 16; ++reg)
        out[reg] = ps[reg] * subsc[reg >> 2] * sacc[reg];

    __syncthreads();                                 // ONLY barrier: a_s ready

    #pragma unroll
    for (int ks = 0; ks < 2; ++ks) {
        const short8v af = *(const short8v*)&a_s[wv][m][16 * ks + 8 * half];
        const short8v wf = ks ? wf1 : wf0;
        #pragma unroll
        for (int par = 0; par < 2; ++par) {
            const int s = 2 * ks + par;
            short8v am;
            #pragma unroll
            for (int e = 0; e < 8; ++e) am[e] = (half == par) ? af[e] : (short)0;
            f32x16 p;
            #pragma unroll
            for (int e = 0; e < 16; ++e) p[e] = 0.f;
            p = __builtin_amdgcn_mfma_f32_32x32x16_bf16(am, wf, p, 0, 0, 0);
            float fs[4];
            #pragma unroll
            for (int a = 0; a < 4; ++a)
                fs[a] = fexp2(fminf(es4[a] - es4[s], 120.f));
            #pragma unroll
            for (int reg = 0; reg < 16; ++reg)
                out[reg] += ps[reg] * fs[reg >> 2] * p[reg];
        }
    }

    #pragma unroll
    for (int reg = 0; reg < 16; ++reg) {
        const int irow = (reg & 3) + 8 * (reg >> 2) + 4 * half;
        Op[base + (long)irow * RS + m] = out[reg];
    }
}

} // namespace

extern "C" void kernel_launch(void* const* d_in, const int* in_sizes, int n_in,
                              void* d_out, int out_size, void* d_ws, size_t ws_size,
                              hipStream_t stream)
{
    const float* q = (const float*)d_in[0];
    const float* k = (const float*)d_in[1];
    const float* v = (const float*)d_in[2];
    const float* g = (const float*)d_in[3];
    float* out = (float*)d_out;

    ushort* ChKV = (ushort*)d_ws;                           // 16.8 MB bf16
    float* ChG = (float*)(ChKV + (long)NBH * NC * D * D);   // 1.05 MB f32
    ushort* WT = (ushort*)(ChG + (long)NBH * NC * D);       // 16.8 MB bf16
    ushort* PST = WT + (long)NBH * NC * D * D;              // 16.8 MB bf16
    float* ESb = (float*)(PST + (long)NBH * NC * D * D);    // 4.2 MB f32

    dim3 blk(256);
    k1_stage<<<dim3(NBH * NC), blk, 0, stream>>>(k, v, g, ChKV, ChG, WT, PST, ESb);
    k2_scan<<<dim3(NBH * 4), blk, 0, stream>>>(ChKV, ChG);
    k3_mfma<<<dim3(NBH * NC / 4), blk, 0, stream>>>(q, k, WT, PST, ESb, ChKV, out);
}